// Round 12
// baseline (134.536 us; speedup 1.0000x reference)
//
#include <hip/hip_runtime.h>

typedef unsigned short u16;
typedef unsigned int u32;
typedef __attribute__((ext_vector_type(8))) __bf16 bf16x8;
typedef __attribute__((ext_vector_type(4))) float f32x4;

#define DEVI __device__ __forceinline__
// exp(0.125*d - 16) == exp2(fmaf(d, C1, C2)):
#define C1 0.180336880f    // 0.125 * log2(e)
#define C2 (-23.0831200f)  // -16 * log2(e)

DEVI float bf2f(u16 u) {
    unsigned int v = ((unsigned int)u) << 16;
    return __uint_as_float(v);
}
DEVI u16 f2bf(float f) {
    unsigned int x = __float_as_uint(f);
    x += 0x7fffu + ((x >> 16) & 1u);   // RNE
    return (u16)(x >> 16);
}
DEVI u32 pk2(float lo, float hi) {     // pack 2 f32 -> bf16 pair (RNE)
    union { __bf16 b[2]; u32 u; } c;
    c.b[0] = (__bf16)lo; c.b[1] = (__bf16)hi;
    return c.u;
}
DEVI bf16x8 ldb8(const u16* p) {
    union { uint4 u; bf16x8 b; } c;
    c.u = *(const uint4*)p;
    return c.b;
}
DEVI f32x4 mfma32(bf16x8 a, bf16x8 b, f32x4 c) {
    return __builtin_amdgcn_mfma_f32_16x16x32_bf16(a, b, c, 0, 0, 0);
}
DEVI float clamp4(float v) { return fminf(fmaxf(v, -1e4f), 1e4f); }
DEVI float fexp2(float x) { return __builtin_amdgcn_exp2f(x); }  // v_exp_f32
// async global->LDS, 16B/lane, dest = wave-uniform base + lane*16
DEVI void gld16(const u16* g, u16* l) {
    __builtin_amdgcn_global_load_lds(
        (const __attribute__((address_space(1))) void*)g,
        (__attribute__((address_space(3))) void*)l, 16, 0, 0);
}

// ---------------------------------------------------------------------------
// Kernel 1: prep.  (unchanged)
// ---------------------------------------------------------------------------
__global__ __launch_bounds__(256) void prep(
    const float* __restrict__ wq, const float* __restrict__ wkv,
    const float* __restrict__ wo, const float* __restrict__ x,
    const float* __restrict__ mkf, const float* __restrict__ mvf,
    u16* __restrict__ wqkvT, u16* __restrict__ woT, u16* __restrict__ xb,
    u16* __restrict__ qkv)
{
    const int bid = blockIdx.x, tid = threadIdx.x;
    if (bid < 256) {
        __shared__ u16 T[64][68];
        int j0, k0; const float* W; int ldw; u16* Out;
        if (bid < 192) { int jt = bid % 24, kt = bid / 24;
            j0 = jt * 64; k0 = kt * 64;
            if (j0 < 512) { W = wq + j0;          ldw = 512;  }
            else          { W = wkv + (j0 - 512); ldw = 1024; }
            Out = wqkvT;
        } else { int t = bid - 192;
            j0 = (t >> 3) * 64; k0 = (t & 7) * 64;
            W = wo + j0; ldw = 512; Out = woT;
        }
        const int lr = tid >> 4, lc = tid & 15;
        #pragma unroll
        for (int i = 0; i < 4; ++i) {
            int k = lr + i * 16;
            float4 v = *(const float4*)(W + (size_t)(k0 + k) * ldw + lc * 4);
            u16 p[4] = { f2bf(v.x), f2bf(v.y), f2bf(v.z), f2bf(v.w) };
            *(uint2*)&T[k][lc * 4] = *(uint2*)p;
        }
        __syncthreads();
        #pragma unroll
        for (int i = 0; i < 4; ++i) {
            int j = lr + i * 16;
            u16 p[4];
            #pragma unroll
            for (int c = 0; c < 4; ++c) p[c] = T[lc * 4 + c][j];
            *(uint2*)(Out + (size_t)(j0 + j) * 512 + k0 + lc * 4) = *(uint2*)p;
        }
    } else if (bid < 2304) {
        int e = (bid - 256) * 1024 + tid * 4;
        float4 v = *(const float4*)(x + e);
        u16 p[4] = { f2bf(v.x), f2bf(v.y), f2bf(v.z), f2bf(v.w) };
        *(uint2*)(xb + e) = *(uint2*)p;
    } else {
        int e = (bid - 2304) * 256 + tid;      // 0..131071
        int b = e >> 16, rem = e & 65535;
        int row2 = rem >> 10, c = rem & 1023;  // c<512: K cols, else V cols
        float v = 0.f;
        if (row2 < 3) {
            int hh = (c & 511) >> 6, d = c & 63;
            int src = hh * 192 + row2 * 64 + d;          // flat reshape!
            v = (c < 512) ? 8.0f * mkf[src] : 1.7320508f * mvf[src];
        }
        qkv[((size_t)b * 2112 + 2048 + row2) * 1536 + 512 + c] = f2bf(v);
    }
}

// ---------------------------------------------------------------------------
// Kernel 2: gemmK (unchanged from R11).
// ---------------------------------------------------------------------------
template<int TM, int TN, int BK, bool F32OUT>
__global__ __launch_bounds__(256) void gemmK(
    const u16* __restrict__ A, int lda,
    const u16* __restrict__ BT, int ldb,
    void* __restrict__ Cv, int ldc,
    const float* __restrict__ bias, int K, int mpad)
{
    constexpr int IL = TM / 32, JL = TN / 32, KS = BK / 32;
    __shared__ u16 As[KS][TM * 32];
    __shared__ u16 Bs[KS][TN * 32];

    const int tid = threadIdx.x;
    const int m0 = blockIdx.x * TM, n0 = blockIdx.y * TN;
    const int w = tid >> 6, lane = tid & 63, l15 = lane & 15, quad = lane >> 4;
    const int wr = w >> 1, wc = w & 1;
    const int sr = lane >> 2, sc = (lane & 3) * 8;

    f32x4 acc[IL][JL];
    #pragma unroll
    for (int i = 0; i < IL; ++i)
        #pragma unroll
        for (int j = 0; j < JL; ++j) acc[i][j] = (f32x4){0.f, 0.f, 0.f, 0.f};

    for (int k0 = 0; k0 < K; k0 += BK) {
        __syncthreads();
        #pragma unroll
        for (int p = 0; p < TM / 64; ++p) {
            int r0 = w * (TM / 4) + p * 16;
            const u16* g = A + (size_t)(m0 + r0 + sr) * lda + k0 + sc;
            #pragma unroll
            for (int kk = 0; kk < KS; ++kk)
                gld16(g + 32 * kk, &As[kk][r0 * 32]);
        }
        #pragma unroll
        for (int p = 0; p < TN / 64; ++p) {
            int r0 = w * (TN / 4) + p * 16;
            const u16* g = BT + (size_t)(n0 + r0 + sr) * ldb + k0 + sc;
            #pragma unroll
            for (int kk = 0; kk < KS; ++kk)
                gld16(g + 32 * kk, &Bs[kk][r0 * 32]);
        }
        __syncthreads();

        #pragma unroll
        for (int ks = 0; ks < KS; ++ks) {
            bf16x8 af[IL], bf[JL];
            #pragma unroll
            for (int i = 0; i < IL; ++i)
                af[i] = ldb8(&As[ks][(wr * (TM / 2) + 16 * i + l15) * 32 + quad * 8]);
            #pragma unroll
            for (int j = 0; j < JL; ++j)
                bf[j] = ldb8(&Bs[ks][(wc * (TN / 2) + 16 * j + l15) * 32 + quad * 8]);
            #pragma unroll
            for (int i = 0; i < IL; ++i)
                #pragma unroll
                for (int j = 0; j < JL; ++j)
                    acc[i][j] = mfma32(af[i], bf[j], acc[i][j]);
        }
    }

    #pragma unroll
    for (int j = 0; j < JL; ++j) {
        int col = n0 + wc * (TN / 2) + 16 * j + l15;
        float bv = bias ? bias[col] : 0.f;
        #pragma unroll
        for (int i = 0; i < IL; ++i) {
            #pragma unroll
            for (int r = 0; r < 4; ++r) {
                int row = m0 + wr * (TM / 2) + 16 * i + quad * 4 + r;
                int orow = row + ((row >> 11) * mpad);
                float vr = clamp4(acc[i][j][r] + bv);
                if (F32OUT) ((float*)Cv)[(size_t)orow * ldc + col] = vr;
                else        ((u16*)Cv)[(size_t)orow * ldc + col] = f2bf(vr);
            }
        }
    }
}

// ---------------------------------------------------------------------------
// Kernel 3: flash attention.  R11 geometry (q128, split-K x4, 36.9 KB LDS ->
// 4 blocks/CU) + SOFTWARE-PIPELINED K/V staging: tile kt is loaded into VGPRs
// one iteration ahead (prefetch issued after barrier2, flies during compute),
// so barrier1's vmcnt drain is cheap — global latency off the barrier path.
// ---------------------------------------------------------------------------
__global__ __launch_bounds__(256, 4) void attn_kernel(
    const u16* __restrict__ qkv, u16* __restrict__ Opart,
    float* __restrict__ Lpart)
{
    __shared__ alignas(16) u16 Ks[64][72];
    __shared__ alignas(16) u16 Vt[64][72];
    __shared__ alignas(16) u16 Ps[128][72];

    const int tid = threadIdx.x;
    const int bx = blockIdx.x;
    const int qt = bx >> 2, s = bx & 3;
    const int h = blockIdx.y, b = blockIdx.z;
    const int w = tid >> 6, lane = tid & 63, l15 = lane & 15, quad = lane >> 4;
    const size_t bq = (size_t)b * 2112;
    const int rq = qt * 128;
    const int ro = b * 2048 + qt * 128;

    union { u32 u[4]; bf16x8 b8; } onesu;
    #pragma unroll
    for (int i = 0; i < 4; ++i) onesu.u[i] = 0x3F803F80u;
    const bf16x8 onesf = onesu.b8;

    {
        int row = tid >> 1, cg = (tid & 1) * 32;
        const u16* src = qkv + (bq + rq + row) * 1536 + h * 64 + cg;
        *(uint4*)&Ps[row][cg]      = *(const uint4*)src;
        *(uint4*)&Ps[row][cg + 8]  = *(const uint4*)(src + 8);
        *(uint4*)&Ps[row][cg + 16] = *(const uint4*)(src + 16);
        *(uint4*)&Ps[row][cg + 24] = *(const uint4*)(src + 24);
    }
    __syncthreads();
    bf16x8 qf[2][2];
    #pragma unroll
    for (int sub = 0; sub < 2; ++sub) {
        qf[sub][0] = ldb8(&Ps[64 * sub + 16 * w + l15][quad * 8]);
        qf[sub][1] = ldb8(&Ps[64 * sub + 16 * w + l15][32 + quad * 8]);
    }

    f32x4 Od[2][4], Ol[2];
    #pragma unroll
    for (int sub = 0; sub < 2; ++sub) {
        #pragma unroll
        for (int t = 0; t < 4; ++t) Od[sub][t] = (f32x4){0.f, 0.f, 0.f, 0.f};
        Ol[sub] = (f32x4){0.f, 0.f, 0.f, 0.f};
    }

    const int krow = tid >> 2, kcg = (tid & 3) * 16;
    const int vkp = (tid & 31) * 2, vdg = ((tid >> 5) & 7) * 8;

    const int kt0 = s ? 8 * s + 1 : 0;        // {0,9,17,25}
    const int kt1 = 8 * s + 9;                // {9,17,25,33}

    // ---- prologue: preload tile kt0 into registers ----
    uint4 kr0, kr1, vr0, vr1;
    {
        const u16* ksrc = qkv + (bq + kt0 * 64 + krow) * 1536 + 512 + h * 64 + kcg;
        kr0 = *(const uint4*)ksrc; kr1 = *(const uint4*)(ksrc + 8);
        const u16* vsrc = qkv + (bq + kt0 * 64 + vkp) * 1536 + 1024 + h * 64 + vdg;
        vr0 = *(const uint4*)vsrc; vr1 = *(const uint4*)(vsrc + 1536);
    }

    for (int kt = kt0; kt < kt1; ++kt) {
        __syncthreads();   // barrier1: prior frag reads done; prefetch complete
        *(uint4*)&Ks[krow][kcg]     = kr0;
        *(uint4*)&Ks[krow][kcg + 8] = kr1;
        {
            u32 a0[4] = {vr0.x, vr0.y, vr0.z, vr0.w};
            u32 a1[4] = {vr1.x, vr1.y, vr1.z, vr1.w};
            #pragma unroll
            for (int i = 0; i < 4; ++i) {
                u32 lo = __builtin_amdgcn_perm(a1[i], a0[i], 0x05040100u);
                u32 hi = __builtin_amdgcn_perm(a1[i], a0[i], 0x07060302u);
                *(u32*)&Vt[vdg + 2 * i][vkp]     = lo;
                *(u32*)&Vt[vdg + 2 * i + 1][vkp] = hi;
            }
        }
        __syncthreads();   // barrier2: LDS visible (no outstanding vmem here)

        // ---- prefetch tile kt+1 (clamped in-bounds); overlaps compute ----
        {
            int ktn = (kt + 1 < kt1) ? kt + 1 : kt;
            const u16* ksrc = qkv + (bq + ktn * 64 + krow) * 1536 + 512 + h * 64 + kcg;
            kr0 = *(const uint4*)ksrc; kr1 = *(const uint4*)(ksrc + 8);
            const u16* vsrc = qkv + (bq + ktn * 64 + vkp) * 1536 + 1024 + h * 64 + vdg;
            vr0 = *(const uint4*)vsrc; vr1 = *(const uint4*)(vsrc + 1536);
        }

        f32x4 d[2][4];
        #pragma unroll
        for (int sub = 0; sub < 2; ++sub)
            #pragma unroll
            for (int t = 0; t < 4; ++t) d[sub][t] = (f32x4){0.f, 0.f, 0.f, 0.f};
        #pragma unroll
        for (int ks = 0; ks < 2; ++ks) {
            #pragma unroll
            for (int t = 0; t < 4; ++t) {
                bf16x8 kf = ldb8(&Ks[16 * t + l15][ks * 32 + quad * 8]);
                d[0][t] = mfma32(kf, qf[0][ks], d[0][t]);
                d[1][t] = mfma32(kf, qf[1][ks], d[1][t]);
            }
        }
        if (kt == 32) {
            #pragma unroll
            for (int sub = 0; sub < 2; ++sub) {
                #pragma unroll
                for (int t = 1; t < 4; ++t)
                    d[sub][t] = (f32x4){-1e9f, -1e9f, -1e9f, -1e9f};
                #pragma unroll
                for (int r = 0; r < 4; ++r)
                    if (!(quad == 0 && r < 3)) d[sub][0][r] = -1e9f;
            }
        }

        #pragma unroll
        for (int sub = 0; sub < 2; ++sub)
            #pragma unroll
            for (int t = 0; t < 4; ++t) {
                uint2 pv = { pk2(fexp2(fmaf(d[sub][t][0], C1, C2)),
                                 fexp2(fmaf(d[sub][t][1], C1, C2))),
                             pk2(fexp2(fmaf(d[sub][t][2], C1, C2)),
                                 fexp2(fmaf(d[sub][t][3], C1, C2))) };
                *(uint2*)&Ps[64 * sub + 16 * w + l15][16 * t + 4 * quad] = pv;
            }
        #pragma unroll
        for (int ks = 0; ks < 2; ++ks) {
            bf16x8 af0 = ldb8(&Ps[16 * w + l15][ks * 32 + quad * 8]);
            bf16x8 af1 = ldb8(&Ps[64 + 16 * w + l15][ks * 32 + quad * 8]);
            #pragma unroll
            for (int dt = 0; dt < 4; ++dt) {
                bf16x8 vf = ldb8(&Vt[16 * dt + l15][ks * 32 + quad * 8]);
                Od[0][dt] = mfma32(af0, vf, Od[0][dt]);
                Od[1][dt] = mfma32(af1, vf, Od[1][dt]);
            }
            Ol[0] = mfma32(af0, onesf, Ol[0]);
            Ol[1] = mfma32(af1, onesf, Ol[1]);
        }
    }

    u16* Ob = Opart + (size_t)s * 4096 * 512;
    #pragma unroll
    for (int sub = 0; sub < 2; ++sub) {
        #pragma unroll
        for (int r = 0; r < 4; ++r) {
            int row = ro + 64 * sub + 16 * w + quad * 4 + r;
            #pragma unroll
            for (int dt = 0; dt < 4; ++dt) {
                int col = h * 64 + 16 * dt + l15;
                Ob[(size_t)row * 512 + col] = f2bf(Od[sub][dt][r]);
            }
            if (l15 == 0)
                Lpart[((size_t)s * 4096 + row) * 8 + h] = Ol[sub][r];
        }
    }
}

// ---------------------------------------------------------------------------
// Kernel 4: gemm2f (unchanged from R11).
// ---------------------------------------------------------------------------
__global__ __launch_bounds__(256) void gemm2f(
    const u16* __restrict__ Opart, const float* __restrict__ Lpart,
    const u16* __restrict__ BT, float* __restrict__ Cout,
    const float* __restrict__ bias)
{
    __shared__ u16 As0[64 * 32], As1[64 * 32];
    __shared__ u16 Bs0[64 * 32], Bs1[64 * 32];

    const int tid = threadIdx.x;
    const int m0 = blockIdx.x * 64, n0 = blockIdx.y * 64;
    const int w = tid >> 6, lane = tid & 63, l15 = lane & 15, quad = lane >> 4;
    const int wr = w >> 1, wc = w & 1;
    const int sr = lane >> 2, sc = (lane & 3) * 8;
    const int arow = m0 + w * 16 + sr;

    f32x4 acc[2][2];
    #pragma unroll
    for (int i = 0; i < 2; ++i)
        #pragma unroll
        for (int j = 0; j < 2; ++j) acc[i][j] = (f32x4){0.f, 0.f, 0.f, 0.f};

    const u16* bG = BT + (size_t)(n0 + w * 16 + sr) * 512 + sc;

    for (int k0 = 0; k0 < 512; k0 += 64) {
        const int h = k0 >> 6;
        uint4 oa0[4], oa1[4];
        float ls = 0.f;
        #pragma unroll
        for (int s = 0; s < 4; ++s) {
            const u16* ob = Opart + ((size_t)s * 4096 + arow) * 512 + k0 + sc;
            oa0[s] = *(const uint4*)ob;
            oa1[s] = *(const uint4*)(ob + 32);
            ls += Lpart[((size_t)s * 4096 + arow) * 8 + h];
        }
        float rl = 1.0f / fmaxf(ls, 1e-30f);
        __syncthreads();
        gld16(bG + k0,      &Bs0[w * 16 * 32]);
        gld16(bG + k0 + 32, &Bs1[w * 16 * 32]);
        #pragma unroll
        for (int g2 = 0; g2 < 2; ++g2) {
            u32 pk[4];
            #pragma unroll
            for (int e = 0; e < 4; ++e) {
                float lo = 0.f, hi = 0.f;
                #pragma unroll
                for (int s = 0; s < 4; ++s) {
                    u32 v = g2 ? ((const u32*)&oa1[s])[e] : ((const u32*)&oa0[s])[e];
                    lo += bf2f((u16)(v & 0xffff));
                    hi += bf2f((u16)(v >> 16));
                }
                pk[e] = pk2(lo * rl, hi * rl);
            }
            u16* dst = (g2 ? As1 : As0) + (w * 16 + sr) * 32 + sc;
            *(uint4*)dst = *(uint4*)pk;
        }
        __syncthreads();

        #pragma unroll
        for (int ks = 0; ks < 2; ++ks) {
            const u16* Asel = ks ? As1 : As0;
            const u16* Bsel = ks ? Bs1 : Bs0;
            bf16x8 af[2], bf[2];
            #pragma unroll
            for (int i = 0; i < 2; ++i)
                af[i] = ldb8(&Asel[(wr * 32 + 16 * i + l15) * 32 + quad * 8]);
            #pragma unroll
            for (int j = 0; j < 2; ++j)
                bf[j] = ldb8(&Bsel[(wc * 32 + 16 * j + l15) * 32 + quad * 8]);
            #pragma unroll
            for (int i = 0; i < 2; ++i)
                #pragma unroll
                for (int j = 0; j < 2; ++j)
                    acc[i][j] = mfma32(af[i], bf[j], acc[i][j]);
        }
    }

    #pragma unroll
    for (int j = 0; j < 2; ++j) {
        int col = n0 + wc * 32 + 16 * j + l15;
        float bv = bias[col];
        #pragma unroll
        for (int i = 0; i < 2; ++i) {
            #pragma unroll
            for (int r = 0; r < 4; ++r) {
                int row = m0 + wr * 32 + 16 * i + quad * 4 + r;
                Cout[(size_t)row * 512 + col] = clamp4(acc[i][j][r] + bv);
            }
        }
    }
}

// ---------------------------------------------------------------------------
extern "C" void kernel_launch(void* const* d_in, const int* in_sizes, int n_in,
                              void* d_out, int out_size, void* d_ws, size_t ws_size,
                              hipStream_t stream)
{
    (void)in_sizes; (void)n_in; (void)out_size; (void)ws_size;
    const float* x   = (const float*)d_in[0];
    const float* wq  = (const float*)d_in[1];
    const float* wkv = (const float*)d_in[2];
    const float* wo  = (const float*)d_in[3];
    const float* bo  = (const float*)d_in[4];
    const float* mk  = (const float*)d_in[5];
    const float* mv  = (const float*)d_in[6];
    float* out = (float*)d_out;

    u16* qkv   = (u16*)d_ws;                     // 2*2112*1536
    u16* outp  = qkv + 6488064;                  // (layout slot)
    u16* woT   = outp + 2097152;                 // 512*512
    float* Lpart = (float*)(woT + 262144);       // 4*4096*8 f32
    u16* scratch = (u16*)(Lpart + 163840);
    u16* wqkvT = scratch;                        // phase 1
    u16* xb    = scratch + 786432;               // phase 1
    u16* Opart = scratch;                        // phase 2 (4*4096*512)

    prep<<<2816, 256, 0, stream>>>(wq, wkv, wo, x, mk, mv, wqkvT, woT, xb, qkv);
    gemmK<128, 64, 128, false><<<dim3(32, 24), 256, 0, stream>>>(
        xb, 512, wqkvT, 512, qkv, 1536, nullptr, 512, 64);
    attn_kernel<<<dim3(64, 8, 2), 256, 0, stream>>>(qkv, Opart, Lpart);
    gemm2f<<<dim3(64, 8), 256, 0, stream>>>(Opart, Lpart, woT, out, bo);
}

// Round 13
// 129.665 us; speedup vs baseline: 1.0376x; 1.0376x over previous
//
#include <hip/hip_runtime.h>

typedef unsigned short u16;
typedef unsigned int u32;
typedef __attribute__((ext_vector_type(8))) __bf16 bf16x8;
typedef __attribute__((ext_vector_type(4))) float f32x4;

#define DEVI __device__ __forceinline__
// exp(0.125*d - 16) == exp2(fmaf(d, C1, C2)):
#define C1 0.180336880f    // 0.125 * log2(e)
#define C2 (-23.0831200f)  // -16 * log2(e)

DEVI float bf2f(u16 u) {
    unsigned int v = ((unsigned int)u) << 16;
    return __uint_as_float(v);
}
DEVI u16 f2bf(float f) {
    unsigned int x = __float_as_uint(f);
    x += 0x7fffu + ((x >> 16) & 1u);   // RNE
    return (u16)(x >> 16);
}
DEVI u32 pk2(float lo, float hi) {     // pack 2 f32 -> bf16 pair (RNE)
    union { __bf16 b[2]; u32 u; } c;
    c.b[0] = (__bf16)lo; c.b[1] = (__bf16)hi;
    return c.u;
}
DEVI bf16x8 ldb8(const u16* p) {
    union { uint4 u; bf16x8 b; } c;
    c.u = *(const uint4*)p;
    return c.b;
}
DEVI f32x4 mfma32(bf16x8 a, bf16x8 b, f32x4 c) {
    return __builtin_amdgcn_mfma_f32_16x16x32_bf16(a, b, c, 0, 0, 0);
}
DEVI float clamp4(float v) { return fminf(fmaxf(v, -1e4f), 1e4f); }
DEVI float fexp2(float x) { return __builtin_amdgcn_exp2f(x); }  // v_exp_f32
// async global->LDS, 16B/lane, dest = wave-uniform base + lane*16
DEVI void gld16(const u16* g, u16* l) {
    __builtin_amdgcn_global_load_lds(
        (const __attribute__((address_space(1))) void*)g,
        (__attribute__((address_space(3))) void*)l, 16, 0, 0);
}

// ---------------------------------------------------------------------------
// Kernel 1: prep.
// ---------------------------------------------------------------------------
__global__ __launch_bounds__(256) void prep(
    const float* __restrict__ wq, const float* __restrict__ wkv,
    const float* __restrict__ wo, const float* __restrict__ x,
    const float* __restrict__ mkf, const float* __restrict__ mvf,
    u16* __restrict__ wqkvT, u16* __restrict__ woT, u16* __restrict__ xb,
    u16* __restrict__ qkv)
{
    const int bid = blockIdx.x, tid = threadIdx.x;
    if (bid < 256) {
        __shared__ u16 T[64][68];
        int j0, k0; const float* W; int ldw; u16* Out;
        if (bid < 192) { int jt = bid % 24, kt = bid / 24;
            j0 = jt * 64; k0 = kt * 64;
            if (j0 < 512) { W = wq + j0;          ldw = 512;  }
            else          { W = wkv + (j0 - 512); ldw = 1024; }
            Out = wqkvT;
        } else { int t = bid - 192;
            j0 = (t >> 3) * 64; k0 = (t & 7) * 64;
            W = wo + j0; ldw = 512; Out = woT;
        }
        const int lr = tid >> 4, lc = tid & 15;
        #pragma unroll
        for (int i = 0; i < 4; ++i) {
            int k = lr + i * 16;
            float4 v = *(const float4*)(W + (size_t)(k0 + k) * ldw + lc * 4);
            u16 p[4] = { f2bf(v.x), f2bf(v.y), f2bf(v.z), f2bf(v.w) };
            *(uint2*)&T[k][lc * 4] = *(uint2*)p;
        }
        __syncthreads();
        #pragma unroll
        for (int i = 0; i < 4; ++i) {
            int j = lr + i * 16;
            u16 p[4];
            #pragma unroll
            for (int c = 0; c < 4; ++c) p[c] = T[lc * 4 + c][j];
            *(uint2*)(Out + (size_t)(j0 + j) * 512 + k0 + lc * 4) = *(uint2*)p;
        }
    } else if (bid < 2304) {
        int e = (bid - 256) * 1024 + tid * 4;
        float4 v = *(const float4*)(x + e);
        u16 p[4] = { f2bf(v.x), f2bf(v.y), f2bf(v.z), f2bf(v.w) };
        *(uint2*)(xb + e) = *(uint2*)p;
    } else {
        int e = (bid - 2304) * 256 + tid;      // 0..131071
        int b = e >> 16, rem = e & 65535;
        int row2 = rem >> 10, c = rem & 1023;  // c<512: K cols, else V cols
        float v = 0.f;
        if (row2 < 3) {
            int hh = (c & 511) >> 6, d = c & 63;
            int src = hh * 192 + row2 * 64 + d;          // flat reshape!
            v = (c < 512) ? 8.0f * mkf[src] : 1.7320508f * mvf[src];
        }
        qkv[((size_t)b * 2112 + 2048 + row2) * 1536 + 512 + c] = f2bf(v);
    }
}

// ---------------------------------------------------------------------------
// Kernel 2/5: gemmK — BK=64 as two 32-col sub-stages (m97 LDS geometry,
// conflict-free, gld16).  2x2 wave grid, 256 threads.
// gemm1: <128,64> grid(32,24)=768 = 3/CU.  gemm2: <64,64> grid(64,8)=512 = 2/CU.
// ---------------------------------------------------------------------------
template<int TM, int TN, bool F32OUT>
__global__ __launch_bounds__(256) void gemmK(
    const u16* __restrict__ A, int lda,
    const u16* __restrict__ BT, int ldb,
    void* __restrict__ Cv, int ldc,
    const float* __restrict__ bias, int K, int mpad)
{
    constexpr int IL = TM / 32, JL = TN / 32;
    __shared__ u16 As0[TM * 32], As1[TM * 32];
    __shared__ u16 Bs0[TN * 32], Bs1[TN * 32];

    const int tid = threadIdx.x;
    const int m0 = blockIdx.x * TM, n0 = blockIdx.y * TN;
    const int w = tid >> 6, lane = tid & 63, l15 = lane & 15, quad = lane >> 4;
    const int wr = w >> 1, wc = w & 1;
    const int sr = lane >> 2, sc = (lane & 3) * 8;

    f32x4 acc[IL][JL];
    #pragma unroll
    for (int i = 0; i < IL; ++i)
        #pragma unroll
        for (int j = 0; j < JL; ++j) acc[i][j] = (f32x4){0.f, 0.f, 0.f, 0.f};

    for (int k0 = 0; k0 < K; k0 += 64) {
        __syncthreads();
        #pragma unroll
        for (int p = 0; p < TM / 64; ++p) {
            int r0 = w * (TM / 4) + p * 16;
            const u16* g = A + (size_t)(m0 + r0 + sr) * lda + k0 + sc;
            gld16(g,      &As0[r0 * 32]);
            gld16(g + 32, &As1[r0 * 32]);
        }
        #pragma unroll
        for (int p = 0; p < TN / 64; ++p) {
            int r0 = w * (TN / 4) + p * 16;
            const u16* g = BT + (size_t)(n0 + r0 + sr) * ldb + k0 + sc;
            gld16(g,      &Bs0[r0 * 32]);
            gld16(g + 32, &Bs1[r0 * 32]);
        }
        __syncthreads();

        #pragma unroll
        for (int ks = 0; ks < 2; ++ks) {
            const u16* Asel = ks ? As1 : As0;
            const u16* Bsel = ks ? Bs1 : Bs0;
            bf16x8 af[IL], bf[JL];
            #pragma unroll
            for (int i = 0; i < IL; ++i)
                af[i] = ldb8(&Asel[(wr * (TM / 2) + 16 * i + l15) * 32 + quad * 8]);
            #pragma unroll
            for (int j = 0; j < JL; ++j)
                bf[j] = ldb8(&Bsel[(wc * (TN / 2) + 16 * j + l15) * 32 + quad * 8]);
            #pragma unroll
            for (int i = 0; i < IL; ++i)
                #pragma unroll
                for (int j = 0; j < JL; ++j)
                    acc[i][j] = mfma32(af[i], bf[j], acc[i][j]);
        }
    }

    #pragma unroll
    for (int j = 0; j < JL; ++j) {
        int col = n0 + wc * (TN / 2) + 16 * j + l15;
        float bv = bias ? bias[col] : 0.f;
        #pragma unroll
        for (int i = 0; i < IL; ++i) {
            #pragma unroll
            for (int r = 0; r < 4; ++r) {
                int row = m0 + wr * (TM / 2) + 16 * i + quad * 4 + r;
                int orow = row + ((row >> 11) * mpad);
                float vr = clamp4(acc[i][j][r] + bv);
                if (F32OUT) ((float*)Cv)[(size_t)orow * ldc + col] = vr;
                else        ((u16*)Cv)[(size_t)orow * ldc + col] = f2bf(vr);
            }
        }
    }
}

// ---------------------------------------------------------------------------
// Kernel 3: flash attention.  q-tile 128 (2 subtiles/wave), S^T orientation,
// fixed-max softmax (exp2), l via MFMA against a register ones-fragment.
// split-K x4: blockIdx.x = qt*4 + s; ranges {0-8,9-16,17-24,25-32}.
// LDS: Ks 9K + Vt 9K + Ps 18K = 36,864 B -> 4 blocks/CU (16 waves/CU).
// Inline K/V loads before barrier1 (R12's register prefetch REGRESSED −4.5us:
// loop-carried VGPR chain beats the implicit 16-wave/CU overlap — keep simple).
// ---------------------------------------------------------------------------
__global__ __launch_bounds__(256, 4) void attn_kernel(
    const u16* __restrict__ qkv, u16* __restrict__ Opart,
    float* __restrict__ Lpart)
{
    __shared__ alignas(16) u16 Ks[64][72];
    __shared__ alignas(16) u16 Vt[64][72];
    __shared__ alignas(16) u16 Ps[128][72];   // Q at start, then P (2 subtiles)

    const int tid = threadIdx.x;
    const int bx = blockIdx.x;
    const int qt = bx >> 2, s = bx & 3;
    const int h = blockIdx.y, b = blockIdx.z;
    const int w = tid >> 6, lane = tid & 63, l15 = lane & 15, quad = lane >> 4;
    const size_t bq = (size_t)b * 2112;
    const int rq = qt * 128;
    const int ro = b * 2048 + qt * 128;

    // register ones-fragment for the l-column MFMA (bf16 1.0 = 0x3F80)
    union { u32 u[4]; bf16x8 b8; } onesu;
    #pragma unroll
    for (int i = 0; i < 4; ++i) onesu.u[i] = 0x3F803F80u;
    const bf16x8 onesf = onesu.b8;

    // ---- stage Q 128x64 into Ps (raw; scale folded into exp2) ----
    {
        int row = tid >> 1, cg = (tid & 1) * 32;
        const u16* src = qkv + (bq + rq + row) * 1536 + h * 64 + cg;
        *(uint4*)&Ps[row][cg]      = *(const uint4*)src;
        *(uint4*)&Ps[row][cg + 8]  = *(const uint4*)(src + 8);
        *(uint4*)&Ps[row][cg + 16] = *(const uint4*)(src + 16);
        *(uint4*)&Ps[row][cg + 24] = *(const uint4*)(src + 24);
    }
    __syncthreads();
    bf16x8 qf[2][2];
    #pragma unroll
    for (int sub = 0; sub < 2; ++sub) {
        qf[sub][0] = ldb8(&Ps[64 * sub + 16 * w + l15][quad * 8]);
        qf[sub][1] = ldb8(&Ps[64 * sub + 16 * w + l15][32 + quad * 8]);
    }

    f32x4 Od[2][4], Ol[2];
    #pragma unroll
    for (int sub = 0; sub < 2; ++sub) {
        #pragma unroll
        for (int t = 0; t < 4; ++t) Od[sub][t] = (f32x4){0.f, 0.f, 0.f, 0.f};
        Ol[sub] = (f32x4){0.f, 0.f, 0.f, 0.f};
    }

    const int krow = tid >> 2, kcg = (tid & 3) * 16;
    const int vkp = (tid & 31) * 2, vdg = ((tid >> 5) & 7) * 8;

    const int kt0 = s ? 8 * s + 1 : 0;        // {0,9,17,25}
    const int kt1 = 8 * s + 9;                // {9,17,25,33}
    for (int kt = kt0; kt < kt1; ++kt) {
        // ---- global loads early (K tile + V tile) ----
        const u16* ksrc = qkv + (bq + kt * 64 + krow) * 1536 + 512 + h * 64 + kcg;
        uint4 k0 = *(const uint4*)ksrc, k1 = *(const uint4*)(ksrc + 8);
        const u16* vsrc = qkv + (bq + kt * 64 + vkp) * 1536 + 1024 + h * 64 + vdg;
        uint4 v0 = *(const uint4*)vsrc, v1 = *(const uint4*)(vsrc + 1536);
        __syncthreads();   // prior iter's frag reads done
        *(uint4*)&Ks[krow][kcg]     = k0;
        *(uint4*)&Ks[krow][kcg + 8] = k1;
        {
            u32 a0[4] = {v0.x, v0.y, v0.z, v0.w};
            u32 a1[4] = {v1.x, v1.y, v1.z, v1.w};
            #pragma unroll
            for (int i = 0; i < 4; ++i) {
                u32 lo = __builtin_amdgcn_perm(a1[i], a0[i], 0x05040100u);
                u32 hi = __builtin_amdgcn_perm(a1[i], a0[i], 0x07060302u);
                *(u32*)&Vt[vdg + 2 * i][vkp]     = lo;
                *(u32*)&Vt[vdg + 2 * i + 1][vkp] = hi;
            }
        }
        __syncthreads();

        // ---- S^T = K @ Q^T, 2 subtiles; each kf read feeds 2 MFMA ----
        f32x4 d[2][4];
        #pragma unroll
        for (int sub = 0; sub < 2; ++sub)
            #pragma unroll
            for (int t = 0; t < 4; ++t) d[sub][t] = (f32x4){0.f, 0.f, 0.f, 0.f};
        #pragma unroll
        for (int ks = 0; ks < 2; ++ks) {
            #pragma unroll
            for (int t = 0; t < 4; ++t) {
                bf16x8 kf = ldb8(&Ks[16 * t + l15][ks * 32 + quad * 8]);
                d[0][t] = mfma32(kf, qf[0][ks], d[0][t]);
                d[1][t] = mfma32(kf, qf[1][ks], d[1][t]);
            }
        }
        if (kt == 32) {   // keys 2048..2050 valid -> local key 16t+4quad+r < 3
            #pragma unroll
            for (int sub = 0; sub < 2; ++sub) {
                #pragma unroll
                for (int t = 1; t < 4; ++t)
                    d[sub][t] = (f32x4){-1e9f, -1e9f, -1e9f, -1e9f};
                #pragma unroll
                for (int r = 0; r < 4; ++r)
                    if (!(quad == 0 && r < 3)) d[sub][0][r] = -1e9f;
            }
        }

        // ---- p = exp2(fmaf(d,C1,C2)); b64 stores (wave-private rows) ----
        #pragma unroll
        for (int sub = 0; sub < 2; ++sub)
            #pragma unroll
            for (int t = 0; t < 4; ++t) {
                uint2 pv = { pk2(fexp2(fmaf(d[sub][t][0], C1, C2)),
                                 fexp2(fmaf(d[sub][t][1], C1, C2))),
                             pk2(fexp2(fmaf(d[sub][t][2], C1, C2)),
                                 fexp2(fmaf(d[sub][t][3], C1, C2))) };
                *(uint2*)&Ps[64 * sub + 16 * w + l15][16 * t + 4 * quad] = pv;
            }
        // ---- O += P @ V; l += P @ 1 (register fragment, no LDS read) ----
        #pragma unroll
        for (int ks = 0; ks < 2; ++ks) {
            bf16x8 af0 = ldb8(&Ps[16 * w + l15][ks * 32 + quad * 8]);
            bf16x8 af1 = ldb8(&Ps[64 + 16 * w + l15][ks * 32 + quad * 8]);
            #pragma unroll
            for (int dt = 0; dt < 4; ++dt) {
                bf16x8 vf = ldb8(&Vt[16 * dt + l15][ks * 32 + quad * 8]);
                Od[0][dt] = mfma32(af0, vf, Od[0][dt]);
                Od[1][dt] = mfma32(af1, vf, Od[1][dt]);
            }
            Ol[0] = mfma32(af0, onesf, Ol[0]);
            Ol[1] = mfma32(af1, onesf, Ol[1]);
        }
    }

    // ---- epilogue ----
    u16* Ob = Opart + (size_t)s * 4096 * 512;
    #pragma unroll
    for (int sub = 0; sub < 2; ++sub) {
        #pragma unroll
        for (int r = 0; r < 4; ++r) {
            int row = ro + 64 * sub + 16 * w + quad * 4 + r;
            #pragma unroll
            for (int dt = 0; dt < 4; ++dt) {
                int col = h * 64 + 16 * dt + l15;
                Ob[(size_t)row * 512 + col] = f2bf(Od[sub][dt][r]);
            }
            if (l15 == 0)
                Lpart[((size_t)s * 4096 + row) * 8 + h] = Ol[sub][r];
        }
    }
}

// ---------------------------------------------------------------------------
// Kernel 4: merge 4 bf16 partial slabs -> bf16 outp.
// ---------------------------------------------------------------------------
__global__ __launch_bounds__(256) void merge_kernel(
    const u16* __restrict__ Opart, const float* __restrict__ Lpart,
    u16* __restrict__ outp)
{
    int e = (blockIdx.x * 256 + threadIdx.x) * 4;
    int row = e >> 9, h = (e & 511) >> 6;
    float ax = 0.f, ay = 0.f, az = 0.f, aw = 0.f, l = 0.f;
    #pragma unroll
    for (int s = 0; s < 4; ++s) {
        uint2 pv = *(const uint2*)(Opart + (size_t)s * 4096 * 512 + e);
        ax += bf2f((u16)(pv.x & 0xffff)); ay += bf2f((u16)(pv.x >> 16));
        az += bf2f((u16)(pv.y & 0xffff)); aw += bf2f((u16)(pv.y >> 16));
        l += Lpart[((size_t)s * 4096 + row) * 8 + h];
    }
    float rl = 1.0f / fmaxf(l, 1e-30f);
    u16 p[4] = { f2bf(clamp4(ax * rl)), f2bf(clamp4(ay * rl)),
                 f2bf(clamp4(az * rl)), f2bf(clamp4(aw * rl)) };
    *(uint2*)(outp + e) = *(uint2*)p;
}

// ---------------------------------------------------------------------------
extern "C" void kernel_launch(void* const* d_in, const int* in_sizes, int n_in,
                              void* d_out, int out_size, void* d_ws, size_t ws_size,
                              hipStream_t stream)
{
    (void)in_sizes; (void)n_in; (void)out_size; (void)ws_size;
    const float* x   = (const float*)d_in[0];
    const float* wq  = (const float*)d_in[1];
    const float* wkv = (const float*)d_in[2];
    const float* wo  = (const float*)d_in[3];
    const float* bo  = (const float*)d_in[4];
    const float* mk  = (const float*)d_in[5];
    const float* mv  = (const float*)d_in[6];
    float* out = (float*)d_out;

    u16* qkv   = (u16*)d_ws;                     // 2*2112*1536
    u16* outp  = qkv + 6488064;                  // 4096*512
    u16* woT   = outp + 2097152;                 // 512*512
    float* Lpart = (float*)(woT + 262144);       // 4*4096*8 f32
    u16* scratch = (u16*)(Lpart + 163840);
    u16* wqkvT = scratch;                        // phase 1
    u16* xb    = scratch + 786432;               // phase 1
    u16* Opart = scratch;                        // phase 2 (4*4096*512)

    prep<<<2816, 256, 0, stream>>>(wq, wkv, wo, x, mk, mv, wqkvT, woT, xb, qkv);
    gemmK<128, 64, false><<<dim3(32, 24), 256, 0, stream>>>(
        xb, 512, wqkvT, 512, qkv, 1536, nullptr, 512, 64);
    attn_kernel<<<dim3(64, 8, 2), 256, 0, stream>>>(qkv, Opart, Lpart);
    merge_kernel<<<2048, 256, 0, stream>>>(Opart, Lpart, outp);
    gemmK<64, 64, true><<<dim3(64, 8), 256, 0, stream>>>(
        outp, 512, woT, 512, out, 512, bo, 512, 0);
}